// Round 9
// baseline (2861.869 us; speedup 1.0000x reference)
//
#include <hip/hip_runtime.h>
#include <hip/hip_bf16.h>

typedef __attribute__((ext_vector_type(8))) short bf16x8;
typedef __attribute__((ext_vector_type(4))) float f32x4;
typedef __attribute__((ext_vector_type(2))) float f32x2;

#define EPB 4096         // edges per partition block
#define BUCKET_BITS 7
#define BUCKET_SIZE 128  // nodes per bucket (128x128 f32 LDS acc = 64 KB)
#define MAXBUCK 1024
#define SBINS 512        // src>>8 bins for within-bucket src sort

static __device__ __forceinline__ unsigned short f2bf(float f) {
    union { float f; unsigned u; } v; v.f = f;
    unsigned r = v.u + 0x7FFF + ((v.u >> 16) & 1);
    return (unsigned short)(r >> 16);
}
static __device__ __forceinline__ float asf(unsigned u) {
    union { unsigned u; float f; } v; v.u = u;
    return v.f;
}
// packed bf16 pair -> f32x2 {lo, hi}
static __device__ __forceinline__ f32x2 cvt2(unsigned u) {
    f32x2 r;
    r.x = asf(u << 16);
    r.y = asf(u & 0xFFFF0000u);
    return r;
}
static __device__ __forceinline__ unsigned pk2(float lo, float hi) {
    return ((unsigned)f2bf(hi) << 16) | f2bf(lo);
}

// ================= K1: prep — weight swizzles + per-chunk bucket counts (merged) =================
__global__ __launch_bounds__(256) void prep(const float* __restrict__ Wrel1,
                                            const float* __restrict__ Wroot1,
                                            const float* __restrict__ Wrel2,
                                            const float* __restrict__ Wroot2,
                                            const float* __restrict__ Wlin,
                                            const int* __restrict__ dst,
                                            unsigned short* __restrict__ bsw1,
                                            unsigned short* __restrict__ bsw2,
                                            unsigned short* __restrict__ bswL,
                                            int* __restrict__ bucketTot,
                                            int E, int nblk, int nbuck) {
    __shared__ int h[MAXBUCK];
    int blk = blockIdx.x, t = threadIdx.x;
    if (blk < 256) {
        const float* Wrel  = (blk < 128) ? Wrel1 : Wrel2;
        const float* Wroot = (blk < 128) ? Wroot1 : Wroot2;
        unsigned short* bsw = (blk < 128) ? bsw1 : bsw2;
        int idx = (blk & 127) * 256 + t;  // 32768 total
        int j = idx & 7, L = (idx >> 3) & 63, ct = (idx >> 9) & 15, kt = idx >> 13;
        int k = kt * 32 + ((L >> 4) * 8) + j;
        int c = ct * 16 + (L & 15);
        float v = (c < 128) ? Wrel[k * 128 + c] : Wroot[k * 128 + (c - 128)];
        bsw[idx] = f2bf(v);
    } else if (blk < 304) {
        int idx = (blk - 256) * 256 + t;  // 12288 total
        int tt = idx;
        int j = tt & 7; tt >>= 3;
        int L = tt & 63; tt >>= 6;
        int ct = tt % 3;
        int kt = tt / 3;
        int k = kt * 32 + ((L >> 4) * 8) + j;
        int c = ct * 16 + (L & 15);
        float v = (c < 40) ? Wlin[k * 40 + c] : 0.f;
        bswL[idx] = f2bf(v);
    } else {
        int hb = blk - 304;
        for (int i = t; i < MAXBUCK; i += 256) h[i] = 0;
        __syncthreads();
        int e0 = hb * EPB;
#pragma unroll
        for (int it = 0; it < EPB / 256; it++) {
            int e = e0 + it * 256 + t;
            if (e < E) atomicAdd(&h[dst[e] >> BUCKET_BITS], 1);
        }
        __syncthreads();
        for (int i = t; i < nbuck; i += 256) {
            int c = h[i];
            if (c) atomicAdd(&bucketTot[i], c);
        }
    }
}

// ================= K2: exclusive scan of bucket totals (4 elems/thread, nbuck <= 1024) =================
__global__ __launch_bounds__(256) void bucket_scan(const int* __restrict__ total,
                                                   int* __restrict__ base, int nbuck) {
    __shared__ int s[256];
    int t = threadIdx.x;
    int e[4]; int ps = 0;
#pragma unroll
    for (int k = 0; k < 4; k++) {
        int idx = 4 * t + k;
        e[k] = (idx < nbuck) ? total[idx] : 0;
        ps += e[k];
    }
    s[t] = ps; __syncthreads();
#pragma unroll
    for (int o = 1; o < 256; o <<= 1) {
        int x = (t >= o) ? s[t - o] : 0;
        __syncthreads();
        s[t] += x; __syncthreads();
    }
    int run = s[t] - ps;
#pragma unroll
    for (int k = 0; k < 4; k++) {
        int idx = 4 * t + k;
        if (idx <= nbuck) base[idx] = run;
        run += e[k];
    }
}

// ================= K3: per-chunk LDS counting sort -> bucket-grouped packed records =================
// Ranges claimed via global atomicAdd on bucketCur (order within bucket arbitrary —
// the src-sort kernel re-orders, and agg is an order-insensitive sum).
__global__ __launch_bounds__(256) void edge_part(const int* __restrict__ src,
                                                 const int* __restrict__ dst,
                                                 const int* __restrict__ bucketBase,
                                                 int* __restrict__ bucketCur,
                                                 int* __restrict__ part,
                                                 int E, int nblk, int nbuck) {
    __shared__ int hcnt[MAXBUCK];
    __shared__ int lstart[MAXBUCK];
    __shared__ int cur[MAXBUCK];
    __shared__ int gbase[MAXBUCK];
    __shared__ int s2[256];
    __shared__ int sdst[EPB];  // 16 KB
    __shared__ int ssrc[EPB];  // 16 KB
    int t = threadIdx.x, blk = blockIdx.x;
    int e0 = blk * EPB;
    int cnt = E - e0; if (cnt > EPB) cnt = EPB;
    for (int i = t; i < MAXBUCK; i += 256) hcnt[i] = 0;
    __syncthreads();
    int myd[EPB / 256], mys[EPB / 256];
#pragma unroll
    for (int it = 0; it < EPB / 256; it++) {
        int i = it * 256 + t;
        if (i < cnt) {
            myd[it] = dst[e0 + i];
            mys[it] = src[e0 + i];
            atomicAdd(&hcnt[myd[it] >> BUCKET_BITS], 1);
        }
    }
    __syncthreads();
    // claim global ranges for this chunk's buckets
    for (int i = t; i < nbuck; i += 256) {
        int c = hcnt[i];
        gbase[i] = c ? (bucketBase[i] + atomicAdd(&bucketCur[i], c)) : 0;
    }
    // local exclusive scan of bucket counts (4/thread over 1024 bins)
    int p[4]; int ps = 0;
#pragma unroll
    for (int k = 0; k < 4; k++) { p[k] = hcnt[4 * t + k]; ps += p[k]; }
    s2[t] = ps; __syncthreads();
#pragma unroll
    for (int o = 1; o < 256; o <<= 1) {
        int x = (t >= o) ? s2[t - o] : 0;
        __syncthreads();
        s2[t] += x; __syncthreads();
    }
    int run = s2[t] - ps;
#pragma unroll
    for (int k = 0; k < 4; k++) {
        lstart[4 * t + k] = run;
        cur[4 * t + k] = 0;
        run += p[k];
    }
    __syncthreads();
#pragma unroll
    for (int it = 0; it < EPB / 256; it++) {
        int i = it * 256 + t;
        if (i < cnt) {
            int b = myd[it] >> BUCKET_BITS;
            int pp = lstart[b] + atomicAdd(&cur[b], 1);
            sdst[pp] = myd[it];
            ssrc[pp] = mys[it];
        }
    }
    __syncthreads();
    for (int i = t; i < cnt; i += 256) {
        int d = sdst[i], s = ssrc[i];
        int b = d >> BUCKET_BITS;
        part[gbase[b] + (i - lstart[b])] = ((d & (BUCKET_SIZE - 1)) << 17) | s;
    }
}

// ================= K4: src-sort (blocks 0..nbuck-1) + layer-1 GEMM (rest), merged =================
// Sort branch: counting sort of the bucket's records by src>>8 -> part2 (ascending
// src order => agg's gather streams through src-space; all blocks advance together
// => source band stays L2-resident). GEMM branch: B staged in LDS (as R7).
__global__ __launch_bounds__(256) void sort_gemm1(const int* __restrict__ part,
                                                  const int* __restrict__ bucketBase,
                                                  int* __restrict__ part2,
                                                  const float* __restrict__ x,
                                                  const unsigned short* __restrict__ Bsw,
                                                  const float* __restrict__ bias,
                                                  unsigned short* __restrict__ xr,
                                                  unsigned short* __restrict__ accbf,
                                                  int N, int nbuck) {
    __shared__ unsigned short Bs[32768];  // 64 KB (GEMM branch)
    __shared__ int h2[SBINS];
    __shared__ int lst2[SBINS];
    __shared__ int cur2[SBINS];
    __shared__ int s2[256];
    int t = threadIdx.x;
    if (blockIdx.x < (unsigned)nbuck) {
        int b = blockIdx.x;
        int lo = bucketBase[b], hi = bucketBase[b + 1];
        for (int i = t; i < SBINS; i += 256) h2[i] = 0;
        __syncthreads();
        for (int i = lo + t; i < hi; i += 256)
            atomicAdd(&h2[(part[i] & 0x1FFFF) >> 8], 1);
        __syncthreads();
        int p0 = h2[2 * t], p1 = h2[2 * t + 1];
        int ps = p0 + p1;
        s2[t] = ps; __syncthreads();
#pragma unroll
        for (int o = 1; o < 256; o <<= 1) {
            int x2 = (t >= o) ? s2[t - o] : 0;
            __syncthreads();
            s2[t] += x2; __syncthreads();
        }
        int pbase = s2[t] - ps;
        lst2[2 * t] = pbase; lst2[2 * t + 1] = pbase + p0;
        cur2[2 * t] = 0; cur2[2 * t + 1] = 0;
        __syncthreads();
        for (int i = lo + t; i < hi; i += 256) {
            int rec = part[i];
            int bin = (rec & 0x1FFFF) >> 8;
            int pp = lst2[bin] + atomicAdd(&cur2[bin], 1);
            part2[lo + pp] = rec;
        }
    } else {
        // stage B into LDS (block-uniform branch -> __syncthreads is safe)
        {
            uint4* d4 = (uint4*)Bs;
            const uint4* s4 = (const uint4*)Bsw;
#pragma unroll
            for (int i = 0; i < 16; i++) d4[t + i * 256] = s4[t + i * 256];
        }
        __syncthreads();
        int wid = (blockIdx.x - nbuck) * 4 + (t >> 6);
        int L = t & 63;
        int r0 = wid * 16;
        if (r0 >= N) return;
        int arow = r0 + (L & 15);
        f32x4 acc[16];
#pragma unroll
        for (int i = 0; i < 16; i++) acc[i] = (f32x4){0.f, 0.f, 0.f, 0.f};
#pragma unroll
        for (int kt = 0; kt < 4; kt++) {
            const float* Arow = x + (size_t)arow * 128 + ((L >> 4) * 8) + kt * 32;
            float4 a0 = *(const float4*)Arow;
            float4 a1 = *(const float4*)(Arow + 4);
            bf16x8 a;
            a[0] = (short)f2bf(a0.x); a[1] = (short)f2bf(a0.y);
            a[2] = (short)f2bf(a0.z); a[3] = (short)f2bf(a0.w);
            a[4] = (short)f2bf(a1.x); a[5] = (short)f2bf(a1.y);
            a[6] = (short)f2bf(a1.z); a[7] = (short)f2bf(a1.w);
#pragma unroll
            for (int ct = 0; ct < 16; ct++) {
                bf16x8 b = *(const bf16x8*)(Bs + (((kt * 16 + ct) * 64) + L) * 8);
                acc[ct] = __builtin_amdgcn_mfma_f32_16x16x32_bf16(a, b, acc[ct], 0, 0, 0);
            }
        }
        int rbase = r0 + (L >> 4) * 4;
        int cl = L & 15;
#pragma unroll
        for (int ct = 0; ct < 16; ct++) {
            int col = ct * 16 + cl;
#pragma unroll
            for (int r = 0; r < 4; r++) {
                int row = rbase + r;
                float v = acc[ct][r];
                if (col < 128)
                    xr[(size_t)row * 128 + col] = f2bf(v);
                else
                    accbf[(size_t)row * 128 + (col - 128)] = f2bf(v + bias[col - 128]);
            }
        }
    }
}

// ================= layer-2 GEMM (bf16 A, B staged in LDS, grid-stride tiles) =================
__global__ __launch_bounds__(256) void gemm_layer2(const unsigned short* __restrict__ Abf,
                                                   const unsigned short* __restrict__ Bsw,
                                                   const float* __restrict__ bias,
                                                   unsigned short* __restrict__ xr,
                                                   unsigned short* __restrict__ accbf, int N) {
    __shared__ unsigned short Bs[32768];  // 64 KB
    int t = threadIdx.x;
    {
        uint4* d4 = (uint4*)Bs;
        const uint4* s4 = (const uint4*)Bsw;
#pragma unroll
        for (int i = 0; i < 16; i++) d4[t + i * 256] = s4[t + i * 256];
    }
    __syncthreads();
    int w = t >> 6, L = t & 63;
    int nTiles = (N + 15) / 16;
    for (int tile = blockIdx.x * 4 + w; tile < nTiles; tile += gridDim.x * 4) {
        int r0 = tile * 16;
        int arow = r0 + (L & 15);
        f32x4 acc[16];
#pragma unroll
        for (int i = 0; i < 16; i++) acc[i] = (f32x4){0.f, 0.f, 0.f, 0.f};
#pragma unroll
        for (int kt = 0; kt < 4; kt++) {
            bf16x8 a = *((const bf16x8*)(Abf + (size_t)arow * 128 + ((L >> 4) * 8) + kt * 32));
#pragma unroll
            for (int ct = 0; ct < 16; ct++) {
                bf16x8 b = *(const bf16x8*)(Bs + (((kt * 16 + ct) * 64) + L) * 8);
                acc[ct] = __builtin_amdgcn_mfma_f32_16x16x32_bf16(a, b, acc[ct], 0, 0, 0);
            }
        }
        int rbase = r0 + (L >> 4) * 4;
        int cl = L & 15;
#pragma unroll
        for (int ct = 0; ct < 16; ct++) {
            int col = ct * 16 + cl;
#pragma unroll
            for (int r = 0; r < 4; r++) {
                int row = rbase + r;
                float v = acc[ct][r];
                if (col < 128)
                    xr[(size_t)row * 128 + col] = f2bf(v);
                else
                    accbf[(size_t)row * 128 + (col - 128)] = f2bf(v + bias[col - 128]);
            }
        }
    }
}

// ================= edge-parallel agg: src-sorted stream -> LDS f32 acc, + relu + bf16 =================
// Block per dst-bucket (128 nodes). Records sorted by src => consecutive edges have
// random dst (no same-address LDS trains — R4's killer) and ascending src (gather
// streams; co-resident blocks share the src band -> L2 hits).
// 16 lanes/edge (uint4 each = full 256B row); slot = ((j<<4)|f) ^ (dl&31):
// per ds_add instruction the 16 f-lanes hit 16 distinct banks; XOR spreads edges.
__global__ __launch_bounds__(256) void agg_edge(const unsigned short* __restrict__ xr,
                                                const unsigned short* __restrict__ accbf,
                                                const int* __restrict__ part2,
                                                const int* __restrict__ bucketBase,
                                                unsigned short* __restrict__ out, int N) {
    __shared__ float acc[BUCKET_SIZE * 128];  // 64 KB
    int b = blockIdx.x;
    int t = threadIdx.x;
    {
        f32x4* a4 = (f32x4*)acc;
#pragma unroll
        for (int i = 0; i < 16; i++) a4[t + i * 256] = (f32x4){0.f, 0.f, 0.f, 0.f};
    }
    __syncthreads();
    int lo = bucketBase[b], hi = bucketBase[b + 1];
    int f = t & 15;
    const unsigned short* xp = xr + f * 8;

    auto DS8 = [&](int rec, uint4 p) {
        int dl = rec >> 17;
        float* base = acc + dl * 128;
        int r = dl & 31;
        f32x2 v;
        v = cvt2(p.x);
        atomicAdd(&base[((0 << 4) | f) ^ r], v.x);
        atomicAdd(&base[((1 << 4) | f) ^ r], v.y);
        v = cvt2(p.y);
        atomicAdd(&base[((2 << 4) | f) ^ r], v.x);
        atomicAdd(&base[((3 << 4) | f) ^ r], v.y);
        v = cvt2(p.z);
        atomicAdd(&base[((4 << 4) | f) ^ r], v.x);
        atomicAdd(&base[((5 << 4) | f) ^ r], v.y);
        v = cvt2(p.w);
        atomicAdd(&base[((6 << 4) | f) ^ r], v.x);
        atomicAdd(&base[((7 << 4) | f) ^ r], v.y);
    };

    int i = lo + (t >> 4);
    for (; i + 16 < hi; i += 32) {
        int r0 = part2[i];
        int r1 = part2[i + 16];
        uint4 p0 = *(const uint4*)(xp + (size_t)(r0 & 0x1FFFF) * 128);
        uint4 p1 = *(const uint4*)(xp + (size_t)(r1 & 0x1FFFF) * 128);
        DS8(r0, p0);
        DS8(r1, p1);
    }
    for (; i < hi; i += 16) {
        int r0 = part2[i];
        uint4 p0 = *(const uint4*)(xp + (size_t)(r0 & 0x1FFFF) * 128);
        DS8(r0, p0);
    }
    __syncthreads();

    // epilogue: +root (accbf), relu, bf16, store. Thread t: node t>>1, half t&1 (64 feats).
    int nl = t >> 1;
    int node = b * BUCKET_SIZE + nl;
    if (node >= N) return;
    int half = t & 1;
    int r = nl & 31;
    const float* base = acc + nl * 128;
    size_t go = (size_t)node * 128 + half * 64;  // ushort units
#pragma unroll
    for (int g = 0; g < 8; g++) {
        int fe = half * 8 + g;
        uint4 ab = *(const uint4*)(accbf + go + g * 8);
        uint4 ov;
        f32x2 c;
        c = cvt2(ab.x);
        ov.x = pk2(fmaxf(base[((0 << 4) | fe) ^ r] + c.x, 0.f),
                   fmaxf(base[((1 << 4) | fe) ^ r] + c.y, 0.f));
        c = cvt2(ab.y);
        ov.y = pk2(fmaxf(base[((2 << 4) | fe) ^ r] + c.x, 0.f),
                   fmaxf(base[((3 << 4) | fe) ^ r] + c.y, 0.f));
        c = cvt2(ab.z);
        ov.z = pk2(fmaxf(base[((4 << 4) | fe) ^ r] + c.x, 0.f),
                   fmaxf(base[((5 << 4) | fe) ^ r] + c.y, 0.f));
        c = cvt2(ab.w);
        ov.w = pk2(fmaxf(base[((6 << 4) | fe) ^ r] + c.x, 0.f),
                   fmaxf(base[((7 << 4) | fe) ^ r] + c.y, 0.f));
        *(uint4*)(out + go + g * 8) = ov;
    }
}

// ================= final GEMM + fused log_softmax (B in LDS, grid-stride) =================
__global__ __launch_bounds__(256) void gemm_final_ls(const unsigned short* __restrict__ x1bf,
                                                     const unsigned short* __restrict__ x2bf,
                                                     const unsigned short* __restrict__ Bsw,
                                                     const float* __restrict__ blin,
                                                     float* __restrict__ out, int N) {
    __shared__ unsigned short Bs[12288];  // 24 KB
    int t = threadIdx.x;
    {
        uint4* d4 = (uint4*)Bs;
        const uint4* s4 = (const uint4*)Bsw;
#pragma unroll
        for (int i = 0; i < 6; i++) d4[t + i * 256] = s4[t + i * 256];
    }
    __syncthreads();
    int w = t >> 6, L = t & 63;
    int cl = L & 15;
    float b0 = blin[cl], b1 = blin[16 + cl];
    float b2 = (cl < 8) ? blin[32 + cl] : 0.f;
    int nTiles = (N + 15) / 16;
    for (int tile = blockIdx.x * 4 + w; tile < nTiles; tile += gridDim.x * 4) {
        int r0 = tile * 16;
        int arow = r0 + (L & 15);
        f32x4 acc[3];
#pragma unroll
        for (int i = 0; i < 3; i++) acc[i] = (f32x4){0.f, 0.f, 0.f, 0.f};
#pragma unroll
        for (int kt = 0; kt < 8; kt++) {
            const unsigned short* Ab = (kt < 4) ? x1bf : x2bf;
            int kk = (kt & 3) * 32 + ((L >> 4) * 8);
            bf16x8 a = *((const bf16x8*)(Ab + (size_t)arow * 128 + kk));
#pragma unroll
            for (int ct = 0; ct < 3; ct++) {
                bf16x8 b = *(const bf16x8*)(Bs + (((kt * 3 + ct) * 64) + L) * 8);
                acc[ct] = __builtin_amdgcn_mfma_f32_16x16x32_bf16(a, b, acc[ct], 0, 0, 0);
            }
        }
        int rbase = r0 + (L >> 4) * 4;
#pragma unroll
        for (int r = 0; r < 4; r++) {
            int row = rbase + r;
            float v0 = acc[0][r] + b0;
            float v1 = acc[1][r] + b1;
            float v2 = (cl < 8) ? (acc[2][r] + b2) : -__builtin_inff();
            float m = fmaxf(fmaxf(v0, v1), v2);
#pragma unroll
            for (int off = 8; off >= 1; off >>= 1) m = fmaxf(m, __shfl_xor(m, off, 64));
            float e = __expf(v0 - m) + __expf(v1 - m) + ((cl < 8) ? __expf(v2 - m) : 0.f);
#pragma unroll
            for (int off = 8; off >= 1; off >>= 1) e += __shfl_xor(e, off, 64);
            float ls = m + __logf(e);
            float* op = out + (size_t)row * 40;
            op[cl] = v0 - ls;
            op[16 + cl] = v1 - ls;
            if (cl < 8) op[32 + cl] = v2 - ls;
        }
    }
}

extern "C" void kernel_launch(void* const* d_in, const int* in_sizes, int n_in,
                              void* d_out, int out_size, void* d_ws, size_t ws_size,
                              hipStream_t stream) {
    const float* x      = (const float*)d_in[0];
    const int*   edge   = (const int*)d_in[1];
    const float* Wrel1  = (const float*)d_in[2];
    const float* brel1  = (const float*)d_in[3];
    const float* Wroot1 = (const float*)d_in[4];
    const float* Wrel2  = (const float*)d_in[5];
    const float* brel2  = (const float*)d_in[6];
    const float* Wroot2 = (const float*)d_in[7];
    const float* Wlin   = (const float*)d_in[8];
    const float* blin   = (const float*)d_in[9];

    const int N = in_sizes[0] / 128;
    const int E = in_sizes[1] / 2;
    const int* src = edge;
    const int* dst = edge + E;

    const int nblk  = (E + EPB - 1) / EPB;                    // 391
    const int nbuck = (N + BUCKET_SIZE - 1) / BUCKET_SIZE;    // 782

    char* ws = (char*)d_ws;
    size_t off = 0;
    auto alloc = [&](size_t bytes) -> void* {
        void* p = ws + off;
        off += (bytes + 255) & ~(size_t)255;
        return p;
    };
    unsigned short* x1bf = (unsigned short*)alloc((size_t)N * 128 * 2);
    unsigned short* x2bf = (unsigned short*)alloc((size_t)N * 128 * 2);
    unsigned short* xr   = (unsigned short*)alloc((size_t)N * 128 * 2);
    unsigned short* accbf= (unsigned short*)alloc((size_t)N * 128 * 2);
    unsigned short* bsw1 = (unsigned short*)alloc(32768 * 2);
    unsigned short* bsw2 = (unsigned short*)alloc(32768 * 2);
    unsigned short* bswL = (unsigned short*)alloc(12288 * 2);
    int* ctrs       = (int*)alloc((size_t)(2 * nbuck) * 4);   // bucketTot | bucketCur
    int* bucketTot  = ctrs;
    int* bucketCur  = ctrs + nbuck;
    int* bucketBase = (int*)alloc((size_t)(nbuck + 1) * 4);
    int* part       = (int*)alloc((size_t)E * 4);
    int* part2      = (int*)alloc((size_t)E * 4);

    const int rowTiles = (N + 15) / 16;
    const int gemmBlocks = (rowTiles + 3) / 4;

    // zero bucket counters (stream-ordered, capture-safe)
    hipMemsetAsync(ctrs, 0, (size_t)(2 * nbuck) * 4, stream);
    // K1: weight swizzles + per-chunk bucket counts
    prep<<<304 + nblk, 256, 0, stream>>>(Wrel1, Wroot1, Wrel2, Wroot2, Wlin, dst,
                                         bsw1, bsw2, bswL, bucketTot, E, nblk, nbuck);
    // K2: exclusive scan of bucket totals
    bucket_scan<<<1, 256, 0, stream>>>(bucketTot, bucketBase, nbuck);
    // K3: partition (atomic range-claim per chunk)
    edge_part<<<nblk, 256, 0, stream>>>(src, dst, bucketBase, bucketCur, part, E, nblk, nbuck);
    // K4: within-bucket src-sort (782 blocks) + layer-1 GEMM (LDS-staged B) in one launch
    sort_gemm1<<<nbuck + gemmBlocks, 256, 0, stream>>>(part, bucketBase, part2,
                                                       x, bsw1, brel1, xr, accbf, N, nbuck);
    // K5: layer-1 aggregation (edge-parallel, src-sorted stream)
    agg_edge<<<nbuck, 256, 0, stream>>>(xr, accbf, part2, bucketBase, x1bf, N);
    // K6: layer-2 GEMM (B in LDS, grid-stride)
    gemm_layer2<<<512, 256, 0, stream>>>(x1bf, bsw2, brel2, xr, accbf, N);
    // K7: layer-2 aggregation
    agg_edge<<<nbuck, 256, 0, stream>>>(xr, accbf, part2, bucketBase, x2bf, N);
    // K8: classifier + fused log_softmax (B in LDS, grid-stride)
    gemm_final_ls<<<512, 256, 0, stream>>>(x1bf, x2bf, bswL, blin, (float*)d_out, N);
}

// Round 10
// 350.546 us; speedup vs baseline: 8.1640x; 8.1640x over previous
//
#include <hip/hip_runtime.h>
#include <hip/hip_bf16.h>

typedef __attribute__((ext_vector_type(8))) short bf16x8;
typedef __attribute__((ext_vector_type(4))) float f32x4;
typedef __attribute__((ext_vector_type(2))) float f32x2;

#define EPB 4096         // edges per partition block
#define BUCKET_BITS 8
#define BUCKET_SIZE 256  // nodes per bucket
#define MAXBUCK 512

static __device__ __forceinline__ unsigned short f2bf(float f) {
    union { float f; unsigned u; } v; v.f = f;
    unsigned r = v.u + 0x7FFF + ((v.u >> 16) & 1);
    return (unsigned short)(r >> 16);
}
static __device__ __forceinline__ float asf(unsigned u) {
    union { unsigned u; float f; } v; v.u = u;
    return v.f;
}
// packed bf16 pair -> f32x2 {lo, hi}
static __device__ __forceinline__ f32x2 cvt2(unsigned u) {
    f32x2 r;
    r.x = asf(u << 16);
    r.y = asf(u & 0xFFFF0000u);
    return r;
}

// ================= K1: prep — weight swizzles + per-chunk bucket counts (merged) =================
__global__ __launch_bounds__(256) void prep(const float* __restrict__ Wrel1,
                                            const float* __restrict__ Wroot1,
                                            const float* __restrict__ Wrel2,
                                            const float* __restrict__ Wroot2,
                                            const float* __restrict__ Wlin,
                                            const int* __restrict__ dst,
                                            unsigned short* __restrict__ bsw1,
                                            unsigned short* __restrict__ bsw2,
                                            unsigned short* __restrict__ bswL,
                                            int* __restrict__ bucketTot,
                                            int E, int nblk, int nbuck) {
    __shared__ int h[MAXBUCK];
    int blk = blockIdx.x, t = threadIdx.x;
    if (blk < 256) {
        const float* Wrel  = (blk < 128) ? Wrel1 : Wrel2;
        const float* Wroot = (blk < 128) ? Wroot1 : Wroot2;
        unsigned short* bsw = (blk < 128) ? bsw1 : bsw2;
        int idx = (blk & 127) * 256 + t;  // 32768 total
        int j = idx & 7, L = (idx >> 3) & 63, ct = (idx >> 9) & 15, kt = idx >> 13;
        int k = kt * 32 + ((L >> 4) * 8) + j;
        int c = ct * 16 + (L & 15);
        float v = (c < 128) ? Wrel[k * 128 + c] : Wroot[k * 128 + (c - 128)];
        bsw[idx] = f2bf(v);
    } else if (blk < 304) {
        int idx = (blk - 256) * 256 + t;  // 12288 total
        int tt = idx;
        int j = tt & 7; tt >>= 3;
        int L = tt & 63; tt >>= 6;
        int ct = tt % 3;
        int kt = tt / 3;
        int k = kt * 32 + ((L >> 4) * 8) + j;
        int c = ct * 16 + (L & 15);
        float v = (c < 40) ? Wlin[k * 40 + c] : 0.f;
        bswL[idx] = f2bf(v);
    } else {
        int hb = blk - 304;
        for (int i = t; i < MAXBUCK; i += 256) h[i] = 0;
        __syncthreads();
        int e0 = hb * EPB;
#pragma unroll
        for (int it = 0; it < EPB / 256; it++) {
            int e = e0 + it * 256 + t;
            if (e < E) atomicAdd(&h[dst[e] >> BUCKET_BITS], 1);
        }
        __syncthreads();
        for (int i = t; i < nbuck; i += 256) {
            int c = h[i];
            if (c) atomicAdd(&bucketTot[i], c);
        }
    }
}

// ================= K2: exclusive scan of bucket totals (pair-scan, nbuck <= 512) =================
__global__ __launch_bounds__(256) void bucket_scan(const int* __restrict__ total,
                                                   int* __restrict__ base, int nbuck) {
    __shared__ int s[256];
    int t = threadIdx.x;
    int e0 = (2 * t < nbuck) ? total[2 * t] : 0;
    int e1 = (2 * t + 1 < nbuck) ? total[2 * t + 1] : 0;
    int ps = e0 + e1;
    s[t] = ps; __syncthreads();
#pragma unroll
    for (int o = 1; o < 256; o <<= 1) {
        int x = (t >= o) ? s[t - o] : 0;
        __syncthreads();
        s[t] += x; __syncthreads();
    }
    int pbase = s[t] - ps;
    if (2 * t <= nbuck) base[2 * t] = pbase;
    if (2 * t + 1 <= nbuck) base[2 * t + 1] = pbase + e0;
}

// ================= K3: per-chunk LDS counting sort -> bucket-grouped packed records =================
// Ranges claimed via global atomicAdd on bucketCur (order within bucket arbitrary —
// csrfin re-sorts and agg is an order-insensitive sum).
__global__ __launch_bounds__(256) void edge_part(const int* __restrict__ src,
                                                 const int* __restrict__ dst,
                                                 const int* __restrict__ bucketBase,
                                                 int* __restrict__ bucketCur,
                                                 int* __restrict__ part,
                                                 int E, int nblk, int nbuck) {
    __shared__ int hcnt[MAXBUCK];
    __shared__ int lstart[MAXBUCK];
    __shared__ int cur[MAXBUCK];
    __shared__ int gbase[MAXBUCK];
    __shared__ int s2[256];
    __shared__ int sdst[EPB];  // 16 KB
    __shared__ int ssrc[EPB];  // 16 KB
    int t = threadIdx.x, blk = blockIdx.x;
    int e0 = blk * EPB;
    int cnt = E - e0; if (cnt > EPB) cnt = EPB;
    for (int i = t; i < MAXBUCK; i += 256) hcnt[i] = 0;
    __syncthreads();
    int myd[EPB / 256], mys[EPB / 256];
#pragma unroll
    for (int it = 0; it < EPB / 256; it++) {
        int i = it * 256 + t;
        if (i < cnt) {
            myd[it] = dst[e0 + i];
            mys[it] = src[e0 + i];
            atomicAdd(&hcnt[myd[it] >> BUCKET_BITS], 1);
        }
    }
    __syncthreads();
    // claim global ranges for this chunk's buckets
    for (int i = t; i < nbuck; i += 256) {
        int c = hcnt[i];
        gbase[i] = c ? (bucketBase[i] + atomicAdd(&bucketCur[i], c)) : 0;
    }
    // local exclusive scan of bucket counts
    int p0 = hcnt[2 * t], p1 = hcnt[2 * t + 1];
    int ps = p0 + p1;
    s2[t] = ps; __syncthreads();
#pragma unroll
    for (int o = 1; o < 256; o <<= 1) {
        int x = (t >= o) ? s2[t - o] : 0;
        __syncthreads();
        s2[t] += x; __syncthreads();
    }
    int pbase = s2[t] - ps;
    lstart[2 * t] = pbase; lstart[2 * t + 1] = pbase + p0;
    cur[2 * t] = 0; cur[2 * t + 1] = 0;
    __syncthreads();
#pragma unroll
    for (int it = 0; it < EPB / 256; it++) {
        int i = it * 256 + t;
        if (i < cnt) {
            int b = myd[it] >> BUCKET_BITS;
            int p = lstart[b] + atomicAdd(&cur[b], 1);
            sdst[p] = myd[it];
            ssrc[p] = mys[it];
        }
    }
    __syncthreads();
    for (int i = t; i < cnt; i += 256) {
        int d = sdst[i], s = ssrc[i];
        int b = d >> BUCKET_BITS;
        part[gbase[b] + (i - lstart[b])] = ((d & (BUCKET_SIZE - 1)) << 17) | s;
    }
}

// ================= K4: csr_finalize (blocks 0..nbuck-1) + layer-1 GEMM (rest), merged =================
// GEMM branch stages B in LDS (64 KB): kills the 400 MB L2->L1 B re-read.
__global__ __launch_bounds__(256) void csrfin_gemm1(const int* __restrict__ part,
                                                    const int* __restrict__ bucketBase,
                                                    int* __restrict__ off_,
                                                    int* __restrict__ deg_,
                                                    int* __restrict__ csr_src,
                                                    const float* __restrict__ x,
                                                    const unsigned short* __restrict__ Bsw,
                                                    const float* __restrict__ bias,
                                                    unsigned short* __restrict__ xr,
                                                    unsigned short* __restrict__ accbf,
                                                    int N, int nbuck) {
    __shared__ unsigned short Bs[32768];  // 64 KB (GEMM branch)
    __shared__ int cur[BUCKET_SIZE];
    __shared__ int h[BUCKET_SIZE];
    __shared__ int tsum[256];
    int t = threadIdx.x;
    if (blockIdx.x < (unsigned)nbuck) {
        int b = blockIdx.x;
        int lo = bucketBase[b], hi = bucketBase[b + 1];
        int n0 = b * BUCKET_SIZE;
        h[t] = 0;
        __syncthreads();
        for (int i = lo + t; i < hi; i += 256) atomicAdd(&h[part[i] >> 17], 1);
        __syncthreads();
        int hv = h[t];
        tsum[t] = hv;
        __syncthreads();
#pragma unroll
        for (int o = 1; o < 256; o <<= 1) {
            int xx = (t >= o) ? tsum[t - o] : 0;
            __syncthreads();
            tsum[t] += xx;
            __syncthreads();
        }
        int st = tsum[t] - hv;
        cur[t] = st;
        int node = n0 + t;
        if (node < N) { off_[node] = lo + st; deg_[node] = hv; }
        __syncthreads();
        for (int i = lo + t; i < hi; i += 256) {
            int rec = part[i];
            int p = atomicAdd(&cur[rec >> 17], 1);
            csr_src[lo + p] = rec & 0x1FFFF;
        }
    } else {
        // stage B into LDS (block-uniform branch -> __syncthreads is safe)
        {
            uint4* d4 = (uint4*)Bs;
            const uint4* s4 = (const uint4*)Bsw;
#pragma unroll
            for (int i = 0; i < 16; i++) d4[t + i * 256] = s4[t + i * 256];
        }
        __syncthreads();
        int wid = (blockIdx.x - nbuck) * 4 + (t >> 6);
        int L = t & 63;
        int r0 = wid * 16;
        if (r0 >= N) return;
        int arow = r0 + (L & 15);
        f32x4 acc[16];
#pragma unroll
        for (int i = 0; i < 16; i++) acc[i] = (f32x4){0.f, 0.f, 0.f, 0.f};
#pragma unroll
        for (int kt = 0; kt < 4; kt++) {
            const float* Arow = x + (size_t)arow * 128 + ((L >> 4) * 8) + kt * 32;
            float4 a0 = *(const float4*)Arow;
            float4 a1 = *(const float4*)(Arow + 4);
            bf16x8 a;
            a[0] = (short)f2bf(a0.x); a[1] = (short)f2bf(a0.y);
            a[2] = (short)f2bf(a0.z); a[3] = (short)f2bf(a0.w);
            a[4] = (short)f2bf(a1.x); a[5] = (short)f2bf(a1.y);
            a[6] = (short)f2bf(a1.z); a[7] = (short)f2bf(a1.w);
#pragma unroll
            for (int ct = 0; ct < 16; ct++) {
                bf16x8 b = *(const bf16x8*)(Bs + (((kt * 16 + ct) * 64) + L) * 8);
                acc[ct] = __builtin_amdgcn_mfma_f32_16x16x32_bf16(a, b, acc[ct], 0, 0, 0);
            }
        }
        int rbase = r0 + (L >> 4) * 4;
        int cl = L & 15;
#pragma unroll
        for (int ct = 0; ct < 16; ct++) {
            int col = ct * 16 + cl;
#pragma unroll
            for (int r = 0; r < 4; r++) {
                int row = rbase + r;
                float v = acc[ct][r];
                if (col < 128)
                    xr[(size_t)row * 128 + col] = f2bf(v);
                else
                    accbf[(size_t)row * 128 + (col - 128)] = f2bf(v + bias[col - 128]);
            }
        }
    }
}

// ================= layer-2 GEMM (bf16 A, B staged in LDS, grid-stride tiles) =================
__global__ __launch_bounds__(256) void gemm_layer2(const unsigned short* __restrict__ Abf,
                                                   const unsigned short* __restrict__ Bsw,
                                                   const float* __restrict__ bias,
                                                   unsigned short* __restrict__ xr,
                                                   unsigned short* __restrict__ accbf, int N) {
    __shared__ unsigned short Bs[32768];  // 64 KB
    int t = threadIdx.x;
    {
        uint4* d4 = (uint4*)Bs;
        const uint4* s4 = (const uint4*)Bsw;
#pragma unroll
        for (int i = 0; i < 16; i++) d4[t + i * 256] = s4[t + i * 256];
    }
    __syncthreads();
    int w = t >> 6, L = t & 63;
    int nTiles = (N + 15) / 16;
    for (int tile = blockIdx.x * 4 + w; tile < nTiles; tile += gridDim.x * 4) {
        int r0 = tile * 16;
        int arow = r0 + (L & 15);
        f32x4 acc[16];
#pragma unroll
        for (int i = 0; i < 16; i++) acc[i] = (f32x4){0.f, 0.f, 0.f, 0.f};
#pragma unroll
        for (int kt = 0; kt < 4; kt++) {
            bf16x8 a = *((const bf16x8*)(Abf + (size_t)arow * 128 + ((L >> 4) * 8) + kt * 32));
#pragma unroll
            for (int ct = 0; ct < 16; ct++) {
                bf16x8 b = *(const bf16x8*)(Bs + (((kt * 16 + ct) * 64) + L) * 8);
                acc[ct] = __builtin_amdgcn_mfma_f32_16x16x32_bf16(a, b, acc[ct], 0, 0, 0);
            }
        }
        int rbase = r0 + (L >> 4) * 4;
        int cl = L & 15;
#pragma unroll
        for (int ct = 0; ct < 16; ct++) {
            int col = ct * 16 + cl;
#pragma unroll
            for (int r = 0; r < 4; r++) {
                int row = rbase + r;
                float v = acc[ct][r];
                if (col < 128)
                    xr[(size_t)row * 128 + col] = f2bf(v);
                else
                    accbf[(size_t)row * 128 + (col - 128)] = f2bf(v + bias[col - 128]);
            }
        }
    }
}

// ================= layer-1 aggregation (R0 structure, verbatim) =================
__global__ __launch_bounds__(256) void agg_relu_cvt(const unsigned short* __restrict__ xr,
                                                    const unsigned short* __restrict__ accbf,
                                                    const int* __restrict__ off_,
                                                    const int* __restrict__ deg,
                                                    const int* __restrict__ csr_src,
                                                    unsigned short* __restrict__ out, int N) {
    int node = blockIdx.x * 4 + (threadIdx.x >> 6);
    if (node >= N) return;
    int L = threadIdx.x & 63;
    int g = L >> 4;
    int f = L & 15;
    int o = off_[node];
    int d = deg[node];
    uint4 arow = (uint4){0, 0, 0, 0};
    if (g == 0) arow = *(const uint4*)(accbf + (size_t)node * 128 + f * 8);

    const int* ip = csr_src + o + g;
    const unsigned short* xrf = xr + f * 8;

    f32x2 a0 = (f32x2){0.f, 0.f}, a1 = (f32x2){0.f, 0.f};
    f32x2 a2 = (f32x2){0.f, 0.f}, a3 = (f32x2){0.f, 0.f};

    int d4 = d & ~3;
#pragma unroll 4
    for (int k = 0; k < d4; k += 4) {
        int s = ip[k];  // group-uniform (16 lanes same addr -> broadcast)
        uint4 p = *(const uint4*)(xrf + (size_t)s * 128);
        a0 += cvt2(p.x);
        a1 += cvt2(p.y);
        a2 += cvt2(p.z);
        a3 += cvt2(p.w);
    }
    if (d4 + g < d) {
        int s = ip[d4];
        uint4 p = *(const uint4*)(xrf + (size_t)s * 128);
        a0 += cvt2(p.x);
        a1 += cvt2(p.y);
        a2 += cvt2(p.z);
        a3 += cvt2(p.w);
    }
    a0.x += __shfl_xor(a0.x, 16, 64); a0.y += __shfl_xor(a0.y, 16, 64);
    a1.x += __shfl_xor(a1.x, 16, 64); a1.y += __shfl_xor(a1.y, 16, 64);
    a2.x += __shfl_xor(a2.x, 16, 64); a2.y += __shfl_xor(a2.y, 16, 64);
    a3.x += __shfl_xor(a3.x, 16, 64); a3.y += __shfl_xor(a3.y, 16, 64);
    a0.x += __shfl_xor(a0.x, 32, 64); a0.y += __shfl_xor(a0.y, 32, 64);
    a1.x += __shfl_xor(a1.x, 32, 64); a1.y += __shfl_xor(a1.y, 32, 64);
    a2.x += __shfl_xor(a2.x, 32, 64); a2.y += __shfl_xor(a2.y, 32, 64);
    a3.x += __shfl_xor(a3.x, 32, 64); a3.y += __shfl_xor(a3.y, 32, 64);

    if (g == 0) {
        uint4 wv;
        wv.x = ((unsigned)f2bf(fmaxf(asf(arow.x & 0xFFFF0000u) + a0.y, 0.f)) << 16)
             | f2bf(fmaxf(asf(arow.x << 16) + a0.x, 0.f));
        wv.y = ((unsigned)f2bf(fmaxf(asf(arow.y & 0xFFFF0000u) + a1.y, 0.f)) << 16)
             | f2bf(fmaxf(asf(arow.y << 16) + a1.x, 0.f));
        wv.z = ((unsigned)f2bf(fmaxf(asf(arow.z & 0xFFFF0000u) + a2.y, 0.f)) << 16)
             | f2bf(fmaxf(asf(arow.z << 16) + a2.x, 0.f));
        wv.w = ((unsigned)f2bf(fmaxf(asf(arow.w & 0xFFFF0000u) + a3.y, 0.f)) << 16)
             | f2bf(fmaxf(asf(arow.w << 16) + a3.x, 0.f));
        *(uint4*)(out + (size_t)node * 128 + f * 8) = wv;
    }
}

// ================= FUSED layer-2 aggregation + classifier + log_softmax =================
// Gather identical to agg_relu_cvt, but x2 lands in LDS h[w][128..255] and the node's
// x1 row (sequential read) in h[w][0..127]. Wave 0 then runs the 4-row classifier
// tile (24 MFMAs; rows 4..15 are clamped duplicates, store-guarded) + log_softmax.
// B read directly from global (24 KB -> L1-hot). Eliminates x2bf round-trip + K8 launch.
__global__ __launch_bounds__(256) void agg2_final_ls(const unsigned short* __restrict__ xr,
                                                     const unsigned short* __restrict__ accbf,
                                                     const unsigned short* __restrict__ x1bf,
                                                     const int* __restrict__ off_,
                                                     const int* __restrict__ deg,
                                                     const int* __restrict__ csr_src,
                                                     const unsigned short* __restrict__ BswL,
                                                     const float* __restrict__ blin,
                                                     float* __restrict__ out, int N) {
    __shared__ __align__(16) unsigned short h[4][264];  // 4 rows x (128 x1 | 128 x2 | 8 pad)
    int t = threadIdx.x;
    int w = t >> 6;
    int node = blockIdx.x * 4 + w;
    int L = t & 63;
    int g = L >> 4;
    int f = L & 15;
    if (node < N) {
        int o = off_[node];
        int d = deg[node];
        uint4 arow = (uint4){0, 0, 0, 0};
        if (g == 0) arow = *(const uint4*)(accbf + (size_t)node * 128 + f * 8);

        const int* ip = csr_src + o + g;
        const unsigned short* xrf = xr + f * 8;

        f32x2 a0 = (f32x2){0.f, 0.f}, a1 = (f32x2){0.f, 0.f};
        f32x2 a2 = (f32x2){0.f, 0.f}, a3 = (f32x2){0.f, 0.f};

        int d4 = d & ~3;
#pragma unroll 4
        for (int k = 0; k < d4; k += 4) {
            int s = ip[k];
            uint4 p = *(const uint4*)(xrf + (size_t)s * 128);
            a0 += cvt2(p.x);
            a1 += cvt2(p.y);
            a2 += cvt2(p.z);
            a3 += cvt2(p.w);
        }
        if (d4 + g < d) {
            int s = ip[d4];
            uint4 p = *(const uint4*)(xrf + (size_t)s * 128);
            a0 += cvt2(p.x);
            a1 += cvt2(p.y);
            a2 += cvt2(p.z);
            a3 += cvt2(p.w);
        }
        a0.x += __shfl_xor(a0.x, 16, 64); a0.y += __shfl_xor(a0.y, 16, 64);
        a1.x += __shfl_xor(a1.x, 16, 64); a1.y += __shfl_xor(a1.y, 16, 64);
        a2.x += __shfl_xor(a2.x, 16, 64); a2.y += __shfl_xor(a2.y, 16, 64);
        a3.x += __shfl_xor(a3.x, 16, 64); a3.y += __shfl_xor(a3.y, 16, 64);
        a0.x += __shfl_xor(a0.x, 32, 64); a0.y += __shfl_xor(a0.y, 32, 64);
        a1.x += __shfl_xor(a1.x, 32, 64); a1.y += __shfl_xor(a1.y, 32, 64);
        a2.x += __shfl_xor(a2.x, 32, 64); a2.y += __shfl_xor(a2.y, 32, 64);
        a3.x += __shfl_xor(a3.x, 32, 64); a3.y += __shfl_xor(a3.y, 32, 64);

        if (g == 0) {
            uint4 wv;
            wv.x = ((unsigned)f2bf(fmaxf(asf(arow.x & 0xFFFF0000u) + a0.y, 0.f)) << 16)
                 | f2bf(fmaxf(asf(arow.x << 16) + a0.x, 0.f));
            wv.y = ((unsigned)f2bf(fmaxf(asf(arow.y & 0xFFFF0000u) + a1.y, 0.f)) << 16)
                 | f2bf(fmaxf(asf(arow.y << 16) + a1.x, 0.f));
            wv.z = ((unsigned)f2bf(fmaxf(asf(arow.z & 0xFFFF0000u) + a2.y, 0.f)) << 16)
                 | f2bf(fmaxf(asf(arow.z << 16) + a2.x, 0.f));
            wv.w = ((unsigned)f2bf(fmaxf(asf(arow.w & 0xFFFF0000u) + a3.y, 0.f)) << 16)
                 | f2bf(fmaxf(asf(arow.w << 16) + a3.x, 0.f));
            *(uint4*)(&h[w][128 + f * 8]) = wv;                                    // x2 half
            uint4 x1r = *(const uint4*)(x1bf + (size_t)node * 128 + f * 8);
            *(uint4*)(&h[w][f * 8]) = x1r;                                         // x1 half
        }
    } else if (g == 0) {
        uint4 z = (uint4){0, 0, 0, 0};
        *(uint4*)(&h[w][f * 8]) = z;
        *(uint4*)(&h[w][128 + f * 8]) = z;
    }
    __syncthreads();
    if (t >= 64) return;  // wave 0 computes the tile (no barriers beyond this point)

    int cl = L & 15;
    float b0 = blin[cl], b1 = blin[16 + cl];
    float b2 = (cl < 8) ? blin[32 + cl] : 0.f;
    int r0 = blockIdx.x * 4;
    int lrow = (L & 15) & 3;  // rows 4..15 duplicate rows 0..3 (store-guarded)
    f32x4 acc[3];
#pragma unroll
    for (int i = 0; i < 3; i++) acc[i] = (f32x4){0.f, 0.f, 0.f, 0.f};
#pragma unroll
    for (int kt = 0; kt < 8; kt++) {
        int kk = (kt & 3) * 32 + ((L >> 4) * 8);
        int col = ((kt < 4) ? 0 : 128) + kk;
        bf16x8 a = *(const bf16x8*)(&h[lrow][col]);
#pragma unroll
        for (int ct = 0; ct < 3; ct++) {
            bf16x8 b = *(const bf16x8*)(BswL + (((kt * 3 + ct) * 64) + L) * 8);
            acc[ct] = __builtin_amdgcn_mfma_f32_16x16x32_bf16(a, b, acc[ct], 0, 0, 0);
        }
    }
    bool qzero = ((L >> 4) == 0);
#pragma unroll
    for (int r = 0; r < 4; r++) {
        int row = r0 + (L >> 4) * 4 + r;
        float v0 = acc[0][r] + b0;
        float v1 = acc[1][r] + b1;
        float v2 = (cl < 8) ? (acc[2][r] + b2) : -__builtin_inff();
        float m = fmaxf(fmaxf(v0, v1), v2);
#pragma unroll
        for (int off = 8; off >= 1; off >>= 1) m = fmaxf(m, __shfl_xor(m, off, 64));
        float e = __expf(v0 - m) + __expf(v1 - m) + ((cl < 8) ? __expf(v2 - m) : 0.f);
#pragma unroll
        for (int off = 8; off >= 1; off >>= 1) e += __shfl_xor(e, off, 64);
        float ls = m + __logf(e);
        if (qzero && row < N) {
            float* op = out + (size_t)row * 40;
            op[cl] = v0 - ls;
            op[16 + cl] = v1 - ls;
            if (cl < 8) op[32 + cl] = v2 - ls;
        }
    }
}

extern "C" void kernel_launch(void* const* d_in, const int* in_sizes, int n_in,
                              void* d_out, int out_size, void* d_ws, size_t ws_size,
                              hipStream_t stream) {
    const float* x      = (const float*)d_in[0];
    const int*   edge   = (const int*)d_in[1];
    const float* Wrel1  = (const float*)d_in[2];
    const float* brel1  = (const float*)d_in[3];
    const float* Wroot1 = (const float*)d_in[4];
    const float* Wrel2  = (const float*)d_in[5];
    const float* brel2  = (const float*)d_in[6];
    const float* Wroot2 = (const float*)d_in[7];
    const float* Wlin   = (const float*)d_in[8];
    const float* blin   = (const float*)d_in[9];

    const int N = in_sizes[0] / 128;
    const int E = in_sizes[1] / 2;
    const int* src = edge;
    const int* dst = edge + E;

    const int nblk  = (E + EPB - 1) / EPB;                    // 391
    const int nbuck = (N + BUCKET_SIZE - 1) / BUCKET_SIZE;    // 391

    char* ws = (char*)d_ws;
    size_t off = 0;
    auto alloc = [&](size_t bytes) -> void* {
        void* p = ws + off;
        off += (bytes + 255) & ~(size_t)255;
        return p;
    };
    unsigned short* x1bf = (unsigned short*)alloc((size_t)N * 128 * 2);
    unsigned short* xr   = (unsigned short*)alloc((size_t)N * 128 * 2);
    unsigned short* accbf= (unsigned short*)alloc((size_t)N * 128 * 2);
    unsigned short* bsw1 = (unsigned short*)alloc(32768 * 2);
    unsigned short* bsw2 = (unsigned short*)alloc(32768 * 2);
    unsigned short* bswL = (unsigned short*)alloc(12288 * 2);
    int* ctrs       = (int*)alloc((size_t)(2 * nbuck) * 4);   // bucketTot | bucketCur
    int* bucketTot  = ctrs;
    int* bucketCur  = ctrs + nbuck;
    int* bucketBase = (int*)alloc((size_t)(nbuck + 1) * 4);
    int* part       = (int*)alloc((size_t)E * 4);
    int* csr_src    = (int*)alloc((size_t)E * 4);
    int* off_       = (int*)alloc((size_t)N * 4);
    int* deg_       = (int*)alloc((size_t)N * 4);

    const int rowTiles = (N + 15) / 16;
    const int gemmBlocks = (rowTiles + 3) / 4;
    const int nodeBlocks = (N + 3) / 4;

    // zero bucket counters (stream-ordered, capture-safe)
    hipMemsetAsync(ctrs, 0, (size_t)(2 * nbuck) * 4, stream);
    // K1: weight swizzles + per-chunk bucket counts
    prep<<<304 + nblk, 256, 0, stream>>>(Wrel1, Wroot1, Wrel2, Wroot2, Wlin, dst,
                                         bsw1, bsw2, bswL, bucketTot, E, nblk, nbuck);
    // K2: exclusive scan of bucket totals
    bucket_scan<<<1, 256, 0, stream>>>(bucketTot, bucketBase, nbuck);
    // K3: partition (atomic range-claim per chunk)
    edge_part<<<nblk, 256, 0, stream>>>(src, dst, bucketBase, bucketCur, part, E, nblk, nbuck);
    // K4: CSR finalize (391 blocks) + layer-1 GEMM (LDS-staged B) in one launch
    csrfin_gemm1<<<nbuck + gemmBlocks, 256, 0, stream>>>(part, bucketBase, off_, deg_, csr_src,
                                                         x, bsw1, brel1, xr, accbf, N, nbuck);
    // K5: layer-1 aggregation
    agg_relu_cvt<<<nodeBlocks, 256, 0, stream>>>(xr, accbf, off_, deg_, csr_src, x1bf, N);
    // K6: layer-2 GEMM (B in LDS, grid-stride)
    gemm_layer2<<<512, 256, 0, stream>>>(x1bf, bsw2, brel2, xr, accbf, N);
    // K7: FUSED layer-2 aggregation + classifier + log_softmax
    agg2_final_ls<<<nodeBlocks, 256, 0, stream>>>(xr, accbf, x1bf, off_, deg_, csr_src,
                                                  bswL, blin, (float*)d_out, N);
}

// Round 11
// 329.626 us; speedup vs baseline: 8.6822x; 1.0635x over previous
//
#include <hip/hip_runtime.h>
#include <hip/hip_bf16.h>

typedef __attribute__((ext_vector_type(8))) short bf16x8;
typedef __attribute__((ext_vector_type(4))) float f32x4;
typedef __attribute__((ext_vector_type(2))) float f32x2;

#define EPB 4096         // edges per partition block
#define BUCKET_BITS 8
#define BUCKET_SIZE 256  // nodes per bucket
#define MAXBUCK 512

static __device__ __forceinline__ unsigned short f2bf(float f) {
    union { float f; unsigned u; } v; v.f = f;
    unsigned r = v.u + 0x7FFF + ((v.u >> 16) & 1);
    return (unsigned short)(r >> 16);
}
static __device__ __forceinline__ float asf(unsigned u) {
    union { unsigned u; float f; } v; v.u = u;
    return v.f;
}
// packed bf16 pair -> f32x2 {lo, hi}
static __device__ __forceinline__ f32x2 cvt2(unsigned u) {
    f32x2 r;
    r.x = asf(u << 16);
    r.y = asf(u & 0xFFFF0000u);
    return r;
}

// ================= K1: prep — weight swizzles + edge histogram (merged) =================
__global__ __launch_bounds__(256) void prep(const float* __restrict__ Wrel1,
                                            const float* __restrict__ Wroot1,
                                            const float* __restrict__ Wrel2,
                                            const float* __restrict__ Wroot2,
                                            const float* __restrict__ Wlin,
                                            const int* __restrict__ dst,
                                            unsigned short* __restrict__ bsw1,
                                            unsigned short* __restrict__ bsw2,
                                            unsigned short* __restrict__ bswL,
                                            int* __restrict__ hist,
                                            int E, int nblk, int nbuck) {
    __shared__ int h[MAXBUCK];
    int blk = blockIdx.x, t = threadIdx.x;
    if (blk < 256) {
        const float* Wrel  = (blk < 128) ? Wrel1 : Wrel2;
        const float* Wroot = (blk < 128) ? Wroot1 : Wroot2;
        unsigned short* bsw = (blk < 128) ? bsw1 : bsw2;
        int idx = (blk & 127) * 256 + t;  // 32768 total
        int j = idx & 7, L = (idx >> 3) & 63, ct = (idx >> 9) & 15, kt = idx >> 13;
        int k = kt * 32 + ((L >> 4) * 8) + j;
        int c = ct * 16 + (L & 15);
        float v = (c < 128) ? Wrel[k * 128 + c] : Wroot[k * 128 + (c - 128)];
        bsw[idx] = f2bf(v);
    } else if (blk < 304) {
        int idx = (blk - 256) * 256 + t;  // 12288 total
        int tt = idx;
        int j = tt & 7; tt >>= 3;
        int L = tt & 63; tt >>= 6;
        int ct = tt % 3;
        int kt = tt / 3;
        int k = kt * 32 + ((L >> 4) * 8) + j;
        int c = ct * 16 + (L & 15);
        float v = (c < 40) ? Wlin[k * 40 + c] : 0.f;
        bswL[idx] = f2bf(v);
    } else {
        int hb = blk - 304;
        for (int i = t; i < MAXBUCK; i += 256) h[i] = 0;
        __syncthreads();
        int e0 = hb * EPB;
#pragma unroll
        for (int it = 0; it < EPB / 256; it++) {
            int e = e0 + it * 256 + t;
            if (e < E) atomicAdd(&h[dst[e] >> BUCKET_BITS], 1);
        }
        __syncthreads();
        for (int i = t; i < nbuck; i += 256) hist[i * nblk + hb] = h[i];
    }
}

// ================= K2a: bucket totals =================
__global__ __launch_bounds__(256) void bucket_total(const int* __restrict__ hist,
                                                    int* __restrict__ total, int nblk) {
    __shared__ int s[256];
    int b = blockIdx.x, t = threadIdx.x;
    int v = 0;
    for (int i = t; i < nblk; i += 256) v += hist[b * nblk + i];
    s[t] = v; __syncthreads();
#pragma unroll
    for (int o = 128; o >= 1; o >>= 1) {
        if (t < o) s[t] += s[t + o];
        __syncthreads();
    }
    if (t == 0) total[b] = s[0];
}

// ================= K2b: exclusive scan of bucket totals (pair-scan, nbuck <= 512) =================
__global__ __launch_bounds__(256) void bucket_scan(const int* __restrict__ total,
                                                   int* __restrict__ base, int nbuck) {
    __shared__ int s[256];
    int t = threadIdx.x;
    int e0 = (2 * t < nbuck) ? total[2 * t] : 0;
    int e1 = (2 * t + 1 < nbuck) ? total[2 * t + 1] : 0;
    int ps = e0 + e1;
    s[t] = ps; __syncthreads();
#pragma unroll
    for (int o = 1; o < 256; o <<= 1) {
        int x = (t >= o) ? s[t - o] : 0;
        __syncthreads();
        s[t] += x; __syncthreads();
    }
    int pbase = s[t] - ps;
    if (2 * t <= nbuck) base[2 * t] = pbase;
    if (2 * t + 1 <= nbuck) base[2 * t + 1] = pbase + e0;
}

// ================= K2c: per-bucket scan over blocks -> global slot bases (in place) =================
__global__ __launch_bounds__(256) void block_scan(int* __restrict__ hist,
                                                  const int* __restrict__ base, int nblk) {
    __shared__ int s[256];
    int b = blockIdx.x, t = threadIdx.x;
    int carryv = base[b];
    for (int start = 0; start < nblk; start += 256) {
        int i = start + t;
        int v = (i < nblk) ? hist[b * nblk + i] : 0;
        s[t] = v; __syncthreads();
#pragma unroll
        for (int o = 1; o < 256; o <<= 1) {
            int x = (t >= o) ? s[t - o] : 0;
            __syncthreads();
            s[t] += x; __syncthreads();
        }
        int excl = s[t] - v + carryv;
        if (i < nblk) hist[b * nblk + i] = excl;
        carryv += s[255];
        __syncthreads();
    }
}

// ================= K3: per-chunk LDS counting sort -> bucket-sorted packed records =================
__global__ __launch_bounds__(256) void edge_part(const int* __restrict__ src,
                                                 const int* __restrict__ dst,
                                                 const int* __restrict__ hist,  // block bases
                                                 int* __restrict__ part,
                                                 int E, int nblk, int nbuck) {
    __shared__ int hcnt[MAXBUCK];
    __shared__ int lstart[MAXBUCK];
    __shared__ int cur[MAXBUCK];
    __shared__ int gbase[MAXBUCK];
    __shared__ int s2[256];
    __shared__ int sdst[EPB];  // 16 KB
    __shared__ int ssrc[EPB];  // 16 KB
    int t = threadIdx.x, blk = blockIdx.x;
    int e0 = blk * EPB;
    int cnt = E - e0; if (cnt > EPB) cnt = EPB;
    for (int i = t; i < MAXBUCK; i += 256) hcnt[i] = 0;
    for (int i = t; i < nbuck; i += 256) gbase[i] = hist[i * nblk + blk];
    __syncthreads();
    int myd[EPB / 256], mys[EPB / 256];
#pragma unroll
    for (int it = 0; it < EPB / 256; it++) {
        int i = it * 256 + t;
        if (i < cnt) {
            myd[it] = dst[e0 + i];
            mys[it] = src[e0 + i];
            atomicAdd(&hcnt[myd[it] >> BUCKET_BITS], 1);
        }
    }
    __syncthreads();
    int p0 = hcnt[2 * t], p1 = hcnt[2 * t + 1];
    int ps = p0 + p1;
    s2[t] = ps; __syncthreads();
#pragma unroll
    for (int o = 1; o < 256; o <<= 1) {
        int x = (t >= o) ? s2[t - o] : 0;
        __syncthreads();
        s2[t] += x; __syncthreads();
    }
    int pbase = s2[t] - ps;
    lstart[2 * t] = pbase; lstart[2 * t + 1] = pbase + p0;
    cur[2 * t] = 0; cur[2 * t + 1] = 0;
    __syncthreads();
#pragma unroll
    for (int it = 0; it < EPB / 256; it++) {
        int i = it * 256 + t;
        if (i < cnt) {
            int b = myd[it] >> BUCKET_BITS;
            int p = lstart[b] + atomicAdd(&cur[b], 1);
            sdst[p] = myd[it];
            ssrc[p] = mys[it];
        }
    }
    __syncthreads();
    for (int i = t; i < cnt; i += 256) {
        int d = sdst[i], s = ssrc[i];
        int b = d >> BUCKET_BITS;
        part[gbase[b] + (i - lstart[b])] = ((d & (BUCKET_SIZE - 1)) << 17) | s;
    }
}

// ================= K4: csr_finalize (blocks 0..nbuck-1) + layer-1 GEMM (rest), merged =================
// GEMM branch stages B in LDS (64 KB): kills the 400 MB L2->L1 B re-read
// (each wave previously streamed the whole 64 KB B from global per tile).
__global__ __launch_bounds__(256) void csrfin_gemm1(const int* __restrict__ part,
                                                    const int* __restrict__ bucketBase,
                                                    int* __restrict__ off_,
                                                    int* __restrict__ deg_,
                                                    int* __restrict__ csr_src,
                                                    const float* __restrict__ x,
                                                    const unsigned short* __restrict__ Bsw,
                                                    const float* __restrict__ bias,
                                                    unsigned short* __restrict__ xr,
                                                    unsigned short* __restrict__ accbf,
                                                    int N, int nbuck) {
    __shared__ unsigned short Bs[32768];  // 64 KB (GEMM branch)
    __shared__ int cur[BUCKET_SIZE];
    __shared__ int h[BUCKET_SIZE];
    __shared__ int tsum[256];
    int t = threadIdx.x;
    if (blockIdx.x < (unsigned)nbuck) {
        int b = blockIdx.x;
        int lo = bucketBase[b], hi = bucketBase[b + 1];
        int n0 = b * BUCKET_SIZE;
        h[t] = 0;
        __syncthreads();
        for (int i = lo + t; i < hi; i += 256) atomicAdd(&h[part[i] >> 17], 1);
        __syncthreads();
        int hv = h[t];
        tsum[t] = hv;
        __syncthreads();
#pragma unroll
        for (int o = 1; o < 256; o <<= 1) {
            int xx = (t >= o) ? tsum[t - o] : 0;
            __syncthreads();
            tsum[t] += xx;
            __syncthreads();
        }
        int st = tsum[t] - hv;
        cur[t] = st;
        int node = n0 + t;
        if (node < N) { off_[node] = lo + st; deg_[node] = hv; }
        __syncthreads();
        for (int i = lo + t; i < hi; i += 256) {
            int rec = part[i];
            int p = atomicAdd(&cur[rec >> 17], 1);
            csr_src[lo + p] = rec & 0x1FFFF;
        }
    } else {
        // stage B into LDS (block-uniform branch -> __syncthreads is safe)
        {
            uint4* d4 = (uint4*)Bs;
            const uint4* s4 = (const uint4*)Bsw;
#pragma unroll
            for (int i = 0; i < 16; i++) d4[t + i * 256] = s4[t + i * 256];
        }
        __syncthreads();
        int wid = (blockIdx.x - nbuck) * 4 + (t >> 6);
        int L = t & 63;
        int r0 = wid * 16;
        if (r0 >= N) return;
        int arow = r0 + (L & 15);
        f32x4 acc[16];
#pragma unroll
        for (int i = 0; i < 16; i++) acc[i] = (f32x4){0.f, 0.f, 0.f, 0.f};
#pragma unroll
        for (int kt = 0; kt < 4; kt++) {
            const float* Arow = x + (size_t)arow * 128 + ((L >> 4) * 8) + kt * 32;
            float4 a0 = *(const float4*)Arow;
            float4 a1 = *(const float4*)(Arow + 4);
            bf16x8 a;
            a[0] = (short)f2bf(a0.x); a[1] = (short)f2bf(a0.y);
            a[2] = (short)f2bf(a0.z); a[3] = (short)f2bf(a0.w);
            a[4] = (short)f2bf(a1.x); a[5] = (short)f2bf(a1.y);
            a[6] = (short)f2bf(a1.z); a[7] = (short)f2bf(a1.w);
#pragma unroll
            for (int ct = 0; ct < 16; ct++) {
                bf16x8 b = *(const bf16x8*)(Bs + (((kt * 16 + ct) * 64) + L) * 8);
                acc[ct] = __builtin_amdgcn_mfma_f32_16x16x32_bf16(a, b, acc[ct], 0, 0, 0);
            }
        }
        int rbase = r0 + (L >> 4) * 4;
        int cl = L & 15;
#pragma unroll
        for (int ct = 0; ct < 16; ct++) {
            int col = ct * 16 + cl;
#pragma unroll
            for (int r = 0; r < 4; r++) {
                int row = rbase + r;
                float v = acc[ct][r];
                if (col < 128)
                    xr[(size_t)row * 128 + col] = f2bf(v);
                else
                    accbf[(size_t)row * 128 + (col - 128)] = f2bf(v + bias[col - 128]);
            }
        }
    }
}

// ================= layer-2 GEMM (bf16 A, B staged in LDS, grid-stride tiles) =================
__global__ __launch_bounds__(256) void gemm_layer2(const unsigned short* __restrict__ Abf,
                                                   const unsigned short* __restrict__ Bsw,
                                                   const float* __restrict__ bias,
                                                   unsigned short* __restrict__ xr,
                                                   unsigned short* __restrict__ accbf, int N) {
    __shared__ unsigned short Bs[32768];  // 64 KB
    int t = threadIdx.x;
    {
        uint4* d4 = (uint4*)Bs;
        const uint4* s4 = (const uint4*)Bsw;
#pragma unroll
        for (int i = 0; i < 16; i++) d4[t + i * 256] = s4[t + i * 256];
    }
    __syncthreads();
    int w = t >> 6, L = t & 63;
    int nTiles = (N + 15) / 16;
    for (int tile = blockIdx.x * 4 + w; tile < nTiles; tile += gridDim.x * 4) {
        int r0 = tile * 16;
        int arow = r0 + (L & 15);
        f32x4 acc[16];
#pragma unroll
        for (int i = 0; i < 16; i++) acc[i] = (f32x4){0.f, 0.f, 0.f, 0.f};
#pragma unroll
        for (int kt = 0; kt < 4; kt++) {
            bf16x8 a = *((const bf16x8*)(Abf + (size_t)arow * 128 + ((L >> 4) * 8) + kt * 32));
#pragma unroll
            for (int ct = 0; ct < 16; ct++) {
                bf16x8 b = *(const bf16x8*)(Bs + (((kt * 16 + ct) * 64) + L) * 8);
                acc[ct] = __builtin_amdgcn_mfma_f32_16x16x32_bf16(a, b, acc[ct], 0, 0, 0);
            }
        }
        int rbase = r0 + (L >> 4) * 4;
        int cl = L & 15;
#pragma unroll
        for (int ct = 0; ct < 16; ct++) {
            int col = ct * 16 + cl;
#pragma unroll
            for (int r = 0; r < 4; r++) {
                int row = rbase + r;
                float v = acc[ct][r];
                if (col < 128)
                    xr[(size_t)row * 128 + col] = f2bf(v);
                else
                    accbf[(size_t)row * 128 + (col - 128)] = f2bf(v + bias[col - 128]);
            }
        }
    }
}

// ================= gather-aggregate + relu + bf16 convert (R0 structure, verbatim) =================
// one wave per node; 4 edges per dwordx4 load; f32x2 accumulators -> v_pk_add_f32
__global__ __launch_bounds__(256) void agg_relu_cvt(const unsigned short* __restrict__ xr,
                                                    const unsigned short* __restrict__ accbf,
                                                    const int* __restrict__ off_,
                                                    const int* __restrict__ deg,
                                                    const int* __restrict__ csr_src,
                                                    unsigned short* __restrict__ out, int N) {
    int node = blockIdx.x * 4 + (threadIdx.x >> 6);
    if (node >= N) return;
    int L = threadIdx.x & 63;
    int g = L >> 4;
    int f = L & 15;
    int o = off_[node];
    int d = deg[node];
    uint4 arow = (uint4){0, 0, 0, 0};
    if (g == 0) arow = *(const uint4*)(accbf + (size_t)node * 128 + f * 8);

    const int* ip = csr_src + o + g;
    const unsigned short* xrf = xr + f * 8;

    f32x2 a0 = (f32x2){0.f, 0.f}, a1 = (f32x2){0.f, 0.f};
    f32x2 a2 = (f32x2){0.f, 0.f}, a3 = (f32x2){0.f, 0.f};

    int d4 = d & ~3;
#pragma unroll 4
    for (int k = 0; k < d4; k += 4) {
        int s = ip[k];  // group-uniform (16 lanes same addr -> broadcast)
        uint4 p = *(const uint4*)(xrf + (size_t)s * 128);
        a0 += cvt2(p.x);
        a1 += cvt2(p.y);
        a2 += cvt2(p.z);
        a3 += cvt2(p.w);
    }
    if (d4 + g < d) {
        int s = ip[d4];
        uint4 p = *(const uint4*)(xrf + (size_t)s * 128);
        a0 += cvt2(p.x);
        a1 += cvt2(p.y);
        a2 += cvt2(p.z);
        a3 += cvt2(p.w);
    }
    a0.x += __shfl_xor(a0.x, 16, 64); a0.y += __shfl_xor(a0.y, 16, 64);
    a1.x += __shfl_xor(a1.x, 16, 64); a1.y += __shfl_xor(a1.y, 16, 64);
    a2.x += __shfl_xor(a2.x, 16, 64); a2.y += __shfl_xor(a2.y, 16, 64);
    a3.x += __shfl_xor(a3.x, 16, 64); a3.y += __shfl_xor(a3.y, 16, 64);
    a0.x += __shfl_xor(a0.x, 32, 64); a0.y += __shfl_xor(a0.y, 32, 64);
    a1.x += __shfl_xor(a1.x, 32, 64); a1.y += __shfl_xor(a1.y, 32, 64);
    a2.x += __shfl_xor(a2.x, 32, 64); a2.y += __shfl_xor(a2.y, 32, 64);
    a3.x += __shfl_xor(a3.x, 32, 64); a3.y += __shfl_xor(a3.y, 32, 64);

    if (g == 0) {
        uint4 wv;
        wv.x = ((unsigned)f2bf(fmaxf(asf(arow.x & 0xFFFF0000u) + a0.y, 0.f)) << 16)
             | f2bf(fmaxf(asf(arow.x << 16) + a0.x, 0.f));
        wv.y = ((unsigned)f2bf(fmaxf(asf(arow.y & 0xFFFF0000u) + a1.y, 0.f)) << 16)
             | f2bf(fmaxf(asf(arow.y << 16) + a1.x, 0.f));
        wv.z = ((unsigned)f2bf(fmaxf(asf(arow.z & 0xFFFF0000u) + a2.y, 0.f)) << 16)
             | f2bf(fmaxf(asf(arow.z << 16) + a2.x, 0.f));
        wv.w = ((unsigned)f2bf(fmaxf(asf(arow.w & 0xFFFF0000u) + a3.y, 0.f)) << 16)
             | f2bf(fmaxf(asf(arow.w << 16) + a3.x, 0.f));
        *(uint4*)(out + (size_t)node * 128 + f * 8) = wv;
    }
}

// ================= final GEMM + fused log_softmax (B in LDS, grid-stride) =================
__global__ __launch_bounds__(256) void gemm_final_ls(const unsigned short* __restrict__ x1bf,
                                                     const unsigned short* __restrict__ x2bf,
                                                     const unsigned short* __restrict__ Bsw,
                                                     const float* __restrict__ blin,
                                                     float* __restrict__ out, int N) {
    __shared__ unsigned short Bs[12288];  // 24 KB
    int t = threadIdx.x;
    {
        uint4* d4 = (uint4*)Bs;
        const uint4* s4 = (const uint4*)Bsw;
#pragma unroll
        for (int i = 0; i < 6; i++) d4[t + i * 256] = s4[t + i * 256];
    }
    __syncthreads();
    int w = t >> 6, L = t & 63;
    int cl = L & 15;
    float b0 = blin[cl], b1 = blin[16 + cl];
    float b2 = (cl < 8) ? blin[32 + cl] : 0.f;
    int nTiles = (N + 15) / 16;
    for (int tile = blockIdx.x * 4 + w; tile < nTiles; tile += gridDim.x * 4) {
        int r0 = tile * 16;
        int arow = r0 + (L & 15);
        f32x4 acc[3];
#pragma unroll
        for (int i = 0; i < 3; i++) acc[i] = (f32x4){0.f, 0.f, 0.f, 0.f};
#pragma unroll
        for (int kt = 0; kt < 8; kt++) {
            const unsigned short* Ab = (kt < 4) ? x1bf : x2bf;
            int kk = (kt & 3) * 32 + ((L >> 4) * 8);
            bf16x8 a = *((const bf16x8*)(Ab + (size_t)arow * 128 + kk));
#pragma unroll
            for (int ct = 0; ct < 3; ct++) {
                bf16x8 b = *(const bf16x8*)(Bs + (((kt * 3 + ct) * 64) + L) * 8);
                acc[ct] = __builtin_amdgcn_mfma_f32_16x16x32_bf16(a, b, acc[ct], 0, 0, 0);
            }
        }
        int rbase = r0 + (L >> 4) * 4;
#pragma unroll
        for (int r = 0; r < 4; r++) {
            int row = rbase + r;
            float v0 = acc[0][r] + b0;
            float v1 = acc[1][r] + b1;
            float v2 = (cl < 8) ? (acc[2][r] + b2) : -__builtin_inff();
            float m = fmaxf(fmaxf(v0, v1), v2);
#pragma unroll
            for (int off = 8; off >= 1; off >>= 1) m = fmaxf(m, __shfl_xor(m, off, 64));
            float e = __expf(v0 - m) + __expf(v1 - m) + ((cl < 8) ? __expf(v2 - m) : 0.f);
#pragma unroll
            for (int off = 8; off >= 1; off >>= 1) e += __shfl_xor(e, off, 64);
            float ls = m + __logf(e);
            float* op = out + (size_t)row * 40;
            op[cl] = v0 - ls;
            op[16 + cl] = v1 - ls;
            if (cl < 8) op[32 + cl] = v2 - ls;
        }
    }
}

extern "C" void kernel_launch(void* const* d_in, const int* in_sizes, int n_in,
                              void* d_out, int out_size, void* d_ws, size_t ws_size,
                              hipStream_t stream) {
    const float* x      = (const float*)d_in[0];
    const int*   edge   = (const int*)d_in[1];
    const float* Wrel1  = (const float*)d_in[2];
    const float* brel1  = (const float*)d_in[3];
    const float* Wroot1 = (const float*)d_in[4];
    const float* Wrel2  = (const float*)d_in[5];
    const float* brel2  = (const float*)d_in[6];
    const float* Wroot2 = (const float*)d_in[7];
    const float* Wlin   = (const float*)d_in[8];
    const float* blin   = (const float*)d_in[9];

    const int N = in_sizes[0] / 128;
    const int E = in_sizes[1] / 2;
    const int* src = edge;
    const int* dst = edge + E;

    const int nblk  = (E + EPB - 1) / EPB;                    // 391
    const int nbuck = (N + BUCKET_SIZE - 1) / BUCKET_SIZE;    // 391

    char* ws = (char*)d_ws;
    size_t off = 0;
    auto alloc = [&](size_t bytes) -> void* {
        void* p = ws + off;
        off += (bytes + 255) & ~(size_t)255;
        return p;
    };
    unsigned short* x1bf = (unsigned short*)alloc((size_t)N * 128 * 2);
    unsigned short* x2bf = (unsigned short*)alloc((size_t)N * 128 * 2);
    unsigned short* xr   = (unsigned short*)alloc((size_t)N * 128 * 2);
    unsigned short* accbf= (unsigned short*)alloc((size_t)N * 128 * 2);
    unsigned short* bsw1 = (unsigned short*)alloc(32768 * 2);
    unsigned short* bsw2 = (unsigned short*)alloc(32768 * 2);
    unsigned short* bswL = (unsigned short*)alloc(12288 * 2);
    int* hist       = (int*)alloc((size_t)nbuck * nblk * 4);
    int* bucketTot  = (int*)alloc((size_t)nbuck * 4);
    int* bucketBase = (int*)alloc((size_t)(nbuck + 1) * 4);
    int* part       = (int*)alloc((size_t)E * 4);
    int* csr_src    = (int*)alloc((size_t)E * 4);
    int* off_       = (int*)alloc((size_t)N * 4);
    int* deg_       = (int*)alloc((size_t)N * 4);

    const int rowTiles = (N + 15) / 16;
    const int gemmBlocks = (rowTiles + 3) / 4;
    const int nodeBlocks = (N + 3) / 4;

    // K1: weight swizzles + edge histogram
    prep<<<304 + nblk, 256, 0, stream>>>(Wrel1, Wroot1, Wrel2, Wroot2, Wlin, dst,
                                         bsw1, bsw2, bswL, hist, E, nblk, nbuck);
    // K2: scans
    bucket_total<<<nbuck, 256, 0, stream>>>(hist, bucketTot, nblk);
    bucket_scan<<<1, 256, 0, stream>>>(bucketTot, bucketBase, nbuck);
    block_scan<<<nbuck, 256, 0, stream>>>(hist, bucketBase, nblk);
    // K3: partition
    edge_part<<<nblk, 256, 0, stream>>>(src, dst, hist, part, E, nblk, nbuck);
    // K4: CSR finalize (391 blocks) + layer-1 GEMM (LDS-staged B) in one launch
    csrfin_gemm1<<<nbuck + gemmBlocks, 256, 0, stream>>>(part, bucketBase, off_, deg_, csr_src,
                                                         x, bsw1, brel1, xr, accbf, N, nbuck);
    // K5: layer-1 aggregation
    agg_relu_cvt<<<nodeBlocks, 256, 0, stream>>>(xr, accbf, off_, deg_, csr_src, x1bf, N);
    // K6: layer-2 GEMM (B in LDS, grid-stride)
    gemm_layer2<<<512, 256, 0, stream>>>(x1bf, bsw2, brel2, xr, accbf, N);
    // K7: layer-2 aggregation
    agg_relu_cvt<<<nodeBlocks, 256, 0, stream>>>(xr, accbf, off_, deg_, csr_src, x2bf, N);
    // K8: classifier + fused log_softmax (B in LDS, grid-stride)
    gemm_final_ls<<<512, 256, 0, stream>>>(x1bf, x2bf, bswL, blin, (float*)d_out, N);
}